// Round 1
// 1637.362 us; speedup vs baseline: 1.3832x; 1.3832x over previous
//
#include <hip/hip_runtime.h>
#include <stdint.h>

typedef unsigned short u16;
typedef __bf16 bf16x8 __attribute__((ext_vector_type(8)));
typedef float f32x4 __attribute__((ext_vector_type(4)));

#define BM 128
#define BN 128
#define BK 32
#define SE 40  // old-path LDS row stride

__device__ __forceinline__ float bf2f(u16 u) {
    return __uint_as_float(((unsigned int)u) << 16);
}
__device__ __forceinline__ u16 f2bf(float f) {
    unsigned int x = __float_as_uint(f);
    return (u16)((x + 0x7fffu + ((x >> 16) & 1u)) >> 16);  // RNE (no NaN inputs in this pipeline)
}

__device__ __forceinline__ void ld8(const u16* p, u16* d) {
    *(uint4*)d = *(const uint4*)p;
}
__device__ __forceinline__ void ld8(const float* p, u16* d) {
    float4 a = *(const float4*)p;
    float4 b = *(const float4*)(p + 4);
    d[0] = f2bf(a.x); d[1] = f2bf(a.y); d[2] = f2bf(a.z); d[3] = f2bf(a.w);
    d[4] = f2bf(b.x); d[5] = f2bf(b.y); d[6] = f2bf(b.z); d[7] = f2bf(b.w);
}

__device__ __forceinline__ void stC(u16* p, float v)  { *p = f2bf(v); }
__device__ __forceinline__ void stC(float* p, float v){ *p = v; }

// async global->LDS, 16B per lane; LDS dest = wave-uniform base + lane*16 (HW rule)
__device__ __forceinline__ void gld_lds16(const u16* g, u16* l) {
    __builtin_amdgcn_global_load_lds(
        (__attribute__((address_space(1))) unsigned int*)(uintptr_t)(const void*)g,
        (__attribute__((address_space(3))) unsigned int*)(uintptr_t)(void*)l,
        16, 0, 0);
}

// ---------------------------------------------------------------------------
// FAST PATH: all-bf16 B-transposed GEMM (m97 structure).
// C[M,N] = A[M,K] * B^T  with A [M,K] row-major (lda), B [N,K] row-major (ldb).
// aMode: 0 -> A + strideAz*bz ; 1 -> A + qkv q-head offset(hz)
// bMode: 0 -> B + strideBz*bz ; 1 -> B + qkv k-head offset(hz)
// causal: 0 none; 1 skip blocks bx>by; 2 kLen=(by+1)*BM
// ---------------------------------------------------------------------------
template <typename TC>
__global__ __launch_bounds__(256) void gemm_bt(
    const u16* __restrict__ A, long strideAz, int aMode, int lda,
    const u16* __restrict__ B, long strideBz, int bMode, int ldb,
    TC* __restrict__ C, long strideCz, int ldc,
    int K, int causal, int zBase)
{
    const int bx = blockIdx.x, by = blockIdx.y, bz = blockIdx.z;
    if (causal == 1 && bx > by) return;
    int kLen = K;
    if (causal == 2) { int kl = (by + 1) * BM; kLen = kl < K ? kl : K; }

    const int hz = bz + zBase;
    const long hoff = (long)((hz >> 2) * 3072 + (hz & 3) * 256);
    const u16* Ab = A + (aMode == 0 ? strideAz * bz : hoff);          // q at +0
    const u16* Bb = B + (bMode == 0 ? strideBz * bz : hoff + 2048);   // k at +2048
    TC* Cb = C + strideCz * bz;

    __shared__ __align__(16) u16 As[128][64];   // linear: global_load_lds needs it
    __shared__ __align__(16) u16 Bs[128][64];

    const int tid  = threadIdx.x;
    const int lane = tid & 63;
    const int wave = tid >> 6;
    const int quad = lane >> 4;
    const int l16  = lane & 15;
    const int mBase = (wave >> 1) * 64;
    const int nBase = (wave & 1) * 64;
    const int row0 = by * BM;
    const int col0 = bx * BN;

    const int sr = (lane >> 3);       // staging row within 8-row chunk
    const int sk = (lane & 7) * 8;    // staging k offset (8 elems = 16B)

    f32x4 acc[4][4] = {};

    for (int k0 = 0; k0 < kLen; k0 += 64) {
        #pragma unroll
        for (int t = 0; t < 4; ++t)
            gld_lds16(Ab + (long)(row0 + wave * 32 + t * 8 + sr) * lda + (k0 + sk),
                      &As[wave * 32 + t * 8][0]);
        #pragma unroll
        for (int t = 0; t < 4; ++t)
            gld_lds16(Bb + (long)(col0 + wave * 32 + t * 8 + sr) * ldb + (k0 + sk),
                      &Bs[wave * 32 + t * 8][0]);
        __syncthreads();   // compiler drains vmcnt before s_barrier

        #pragma unroll
        for (int kk = 0; kk < 2; ++kk) {
            bf16x8 af[4], bfr[4];
            #pragma unroll
            for (int i = 0; i < 4; ++i)
                af[i] = *(const bf16x8*)(&As[mBase + 16 * i + l16][kk * 32 + quad * 8]);
            #pragma unroll
            for (int j = 0; j < 4; ++j)
                bfr[j] = *(const bf16x8*)(&Bs[nBase + 16 * j + l16][kk * 32 + quad * 8]);
            #pragma unroll
            for (int i = 0; i < 4; ++i)
                #pragma unroll
                for (int j = 0; j < 4; ++j)
                    acc[i][j] = __builtin_amdgcn_mfma_f32_16x16x32_bf16(af[i], bfr[j], acc[i][j], 0, 0, 0);
        }
        __syncthreads();
    }

    #pragma unroll
    for (int i = 0; i < 4; ++i) {
        const int r0 = row0 + mBase + 16 * i + quad * 4;
        #pragma unroll
        for (int j = 0; j < 4; ++j) {
            const int c = col0 + nBase + 16 * j + l16;
            #pragma unroll
            for (int r = 0; r < 4; ++r)
                stC(&Cb[(long)(r0 + r) * ldc + c], acc[i][j][r]);
        }
    }
}

// f32 -> bf16 elementwise, 8 elems/thread
__global__ __launch_bounds__(256) void cvt_kernel(const float* __restrict__ in,
                                                  u16* __restrict__ out, long n8)
{
    long i = (long)blockIdx.x * 256 + threadIdx.x;
    const long stride = (long)gridDim.x * 256;
    for (; i < n8; i += stride) {
        const float* p = in + i * 8;
        u16 d[8];
        ld8(p, d);
        *(uint4*)(out + i * 8) = *(uint4*)d;
    }
}

// 64x64 tiled transpose -> bf16. in logical [R][C] (ldin), out [C][R] (ldout).
// grid = (C/64, R/64, Z). inMode: 0 -> in + inZ*z ; 1 -> qkv V-head offset(z)
__device__ __forceinline__ void ld4(const float* p, u16* d) {
    float4 v = *(const float4*)p;
    d[0] = f2bf(v.x); d[1] = f2bf(v.y); d[2] = f2bf(v.z); d[3] = f2bf(v.w);
}
__device__ __forceinline__ void ld4(const u16* p, u16* d) {
    *(uint2*)d = *(const uint2*)p;
}

template <typename TIn>
__global__ __launch_bounds__(256) void transpose_kernel(
    const TIn* __restrict__ in, int ldin, int inMode, long inZ,
    u16* __restrict__ out, int ldout, long outZ)
{
    __shared__ u16 t[64][68];  // stride 68: 8B-aligned uint2 stores, mild read conflicts only
    const int bx = blockIdx.x, by = blockIdx.y, bz = blockIdx.z;
    const TIn* inb = in + (inMode == 0 ? inZ * bz
                          : (long)((bz >> 2) * 3072 + 1024 + (bz & 3) * 256));
    u16* outb = out + outZ * bz;
    const int tid = threadIdx.x;
    const int r0 = by * 64;
    const int c0 = bx * 64;
    const int lr = tid >> 4;
    const int lc = (tid & 15) * 4;
    #pragma unroll
    for (int i = 0; i < 4; ++i) {
        u16 d[4];
        ld4(inb + (long)(r0 + lr + i * 16) * ldin + (c0 + lc), d);
        *(uint2*)(&t[lr + i * 16][lc]) = *(uint2*)d;
    }
    __syncthreads();
    const int oc  = tid >> 3;
    const int oro = (tid & 7) * 8;
    #pragma unroll
    for (int i = 0; i < 2; ++i) {
        u16 d[8];
        #pragma unroll
        for (int j = 0; j < 8; ++j) d[j] = t[oro + j][oc + i * 32];
        *(uint4*)(outb + (long)(c0 + oc + i * 32) * ldout + (r0 + oro)) = *(uint4*)d;
    }
}

// ---------------------------------------------------------------------------
// FALLBACK (old) generic GEMM — used only if workspace is too small.
// ---------------------------------------------------------------------------
template <bool BT, typename TA, typename TB, typename TC>
__global__ __launch_bounds__(256) void gemm_bf16(
    const TA* __restrict__ A, long strideAz, int aMode, int lda,
    const TB* __restrict__ B, long strideBz, int bMode, int ldb,
    TC* __restrict__ C, long strideCz, int ldc,
    int K, int causal, int zBase)
{
    const int bx = blockIdx.x, by = blockIdx.y, bz = blockIdx.z;
    if (causal == 1 && bx > by) return;
    int kLen = K;
    if (causal == 2) { int kl = (by + 1) * BM; kLen = kl < K ? kl : K; }

    const int hz = bz + zBase;
    const long hoff = (long)((hz >> 2) * 3072 + (hz & 3) * 256);
    const TA* Ab = A + (aMode == 0 ? strideAz * bz : hoff + (long)(aMode - 1) * 1024);
    const TB* Bb = B + (bMode == 0 ? strideBz * bz : hoff + (long)(bMode - 1) * 1024);
    TC* Cb = C + strideCz * bz;

    __shared__ __align__(16) u16 As[BM][SE];
    __shared__ __align__(16) u16 Bs[BN][SE];

    const int tid  = threadIdx.x;
    const int lane = tid & 63;
    const int wave = tid >> 6;
    const int quad = lane >> 4;
    const int l16  = lane & 15;
    const int mBase = (wave >> 1) * 64;
    const int nBase = (wave & 1) * 64;

    const int row0 = by * BM;
    const int col0 = bx * BN;

    const int ar = tid >> 2;
    const int ac = (tid & 3) * 8;
    const int bk = tid & 15;
    const int bg = tid >> 4;

    f32x4 acc[4][4] = {};

    for (int k0 = 0; k0 < kLen; k0 += BK) {
        {
            u16 t0[8], t1[8];
            ld8(Ab + (long)(row0 + ar) * lda + (k0 + ac), t0);
            ld8(Ab + (long)(row0 + ar + 64) * lda + (k0 + ac), t1);
            *(uint4*)(&As[ar][ac])      = *(uint4*)t0;
            *(uint4*)(&As[ar + 64][ac]) = *(uint4*)t1;
        }
        if (BT) {
            u16 t0[8], t1[8];
            ld8(Bb + (long)(col0 + ar) * ldb + (k0 + ac), t0);
            ld8(Bb + (long)(col0 + ar + 64) * ldb + (k0 + ac), t1);
            *(uint4*)(&Bs[ar][ac])      = *(uint4*)t0;
            *(uint4*)(&Bs[ar + 64][ac]) = *(uint4*)t1;
        } else {
            u16 s0[8], s1[8];
            ld8(Bb + (long)(k0 + bk) * ldb + (col0 + bg * 8), s0);
            ld8(Bb + (long)(k0 + bk + 16) * ldb + (col0 + bg * 8), s1);
            #pragma unroll
            for (int j = 0; j < 8; ++j) {
                const int jj = (j + 2 * bg) & 7;
                Bs[bg * 8 + jj][bk]      = s0[jj];
                Bs[bg * 8 + jj][bk + 16] = s1[jj];
            }
        }
        __syncthreads();

        bf16x8 af[4], bfr[4];
        #pragma unroll
        for (int i = 0; i < 4; ++i)
            af[i] = *(const bf16x8*)(&As[mBase + 16 * i + l16][quad * 8]);
        #pragma unroll
        for (int j = 0; j < 4; ++j)
            bfr[j] = *(const bf16x8*)(&Bs[nBase + 16 * j + l16][quad * 8]);
        #pragma unroll
        for (int i = 0; i < 4; ++i)
            #pragma unroll
            for (int j = 0; j < 4; ++j)
                acc[i][j] = __builtin_amdgcn_mfma_f32_16x16x32_bf16(af[i], bfr[j], acc[i][j], 0, 0, 0);
        __syncthreads();
    }

    #pragma unroll
    for (int i = 0; i < 4; ++i) {
        const int r0 = row0 + mBase + 16 * i + quad * 4;
        #pragma unroll
        for (int j = 0; j < 4; ++j) {
            const int c = col0 + nBase + 16 * j + l16;
            #pragma unroll
            for (int r = 0; r < 4; ++r)
                stC(&Cb[(long)(r0 + r) * ldc + c], acc[i][j][r]);
        }
    }
}

// In-place GPT-J rotary on q,k + fold 1/sqrt(D)=1/16 into q.
__global__ __launch_bounds__(256) void rotary_kernel(u16* __restrict__ qkv,
                                                     const int* __restrict__ pos_ids)
{
    const long bs = blockIdx.x;
    const float pos = (float)pos_ids[bs];
    u16* row = qkv + bs * 12288;
    for (int idx = threadIdx.x; idx < 16 * 224; idx += 256) {
        const int h = idx / 224;
        const int r = idx - h * 224;
        const int base = (h >> 2) * 3072 + (h & 3) * 256;
        if (r < 32) {
            const float invf = powf(10000.0f, (-2.0f * (float)r) * (1.0f / 64.0f));
            float s, c;
            sincosf(pos * invf, &s, &c);
            const int d0 = base + 2 * r;
            const int k0 = d0 + 2048;
            float q0 = bf2f(row[d0]), q1 = bf2f(row[d0 + 1]);
            float ka = bf2f(row[k0]), kb = bf2f(row[k0 + 1]);
            row[d0]     = f2bf((q0 * c - q1 * s) * 0.0625f);
            row[d0 + 1] = f2bf((q1 * c + q0 * s) * 0.0625f);
            row[k0]     = f2bf(ka * c - kb * s);
            row[k0 + 1] = f2bf(kb * c + ka * s);
        } else {
            const int d = base + 64 + (r - 32);
            row[d] = f2bf(bf2f(row[d]) * 0.0625f);
        }
    }
}

// Causal row softmax
__global__ __launch_bounds__(256) void softmax_kernel(u16* __restrict__ scores)
{
    const int qi = blockIdx.x;
    const int h  = blockIdx.y;
    u16* row = scores + ((long)h * 2048 + qi) * 2048;
    const int tid = threadIdx.x;
    const int n = qi + 1;

    float vals[8];
    float lmax = -3.0e38f;
    #pragma unroll
    for (int i = 0; i < 8; ++i) {
        const int j = tid + i * 256;
        const float v = (j < n) ? bf2f(row[j]) : -3.0e38f;
        vals[i] = v;
        lmax = fmaxf(lmax, v);
    }
    __shared__ float red[4];
    #pragma unroll
    for (int off = 32; off > 0; off >>= 1) lmax = fmaxf(lmax, __shfl_down(lmax, off));
    if ((tid & 63) == 0) red[tid >> 6] = lmax;
    __syncthreads();
    lmax = fmaxf(fmaxf(red[0], red[1]), fmaxf(red[2], red[3]));

    float lsum = 0.f;
    #pragma unroll
    for (int i = 0; i < 8; ++i) {
        const int j = tid + i * 256;
        const float e = (j < n) ? expf(vals[i] - lmax) : 0.f;
        vals[i] = e;
        lsum += e;
    }
    #pragma unroll
    for (int off = 32; off > 0; off >>= 1) lsum += __shfl_down(lsum, off);
    __syncthreads();
    if ((tid & 63) == 0) red[tid >> 6] = lsum;
    __syncthreads();
    lsum = red[0] + red[1] + red[2] + red[3];
    const float inv = 1.0f / lsum;
    #pragma unroll
    for (int i = 0; i < 8; ++i)
        row[tid + i * 256] = f2bf(vals[i] * inv);
}

extern "C" void kernel_launch(void* const* d_in, const int* in_sizes, int n_in,
                              void* d_out, int out_size, void* d_ws, size_t ws_size,
                              hipStream_t stream)
{
    const float* hidden = (const float*)d_in[0];
    const float* w_qkv  = (const float*)d_in[1];
    const float* w_out  = (const float*)d_in[2];
    const int*   pos    = (const int*)d_in[3];
    float* out = (float*)d_out;

    const int Bn = 2, S = 2048, E = 4096, H = 16;
    const int N3 = 3 * E;  // 12288
    const size_t per_head = (size_t)S * S * 2;  // 8 MiB

    dim3 blk(256);

    // ---------------- fast path layout (bf16, bytes) ----------------
    // wqkvT 96M | woutT 32M | hb 32M (2 batches) | qkvb 48M | vT 16M | attnb 16M | sc hc*8M
    const size_t fixed =
        (size_t)N3 * E * 2 +        // wqkvT
        (size_t)E * E * 2 +         // woutT
        (size_t)Bn * S * E * 2 +    // hb
        (size_t)S * N3 * 2 +        // qkvb
        (size_t)H * 256 * S * 2 +   // vT
        (size_t)S * E * 2;          // attnb

    if (ws_size >= fixed + per_head) {
        u16* wqkvT = (u16*)d_ws;
        u16* woutT = wqkvT + (size_t)N3 * E;
        u16* hb    = woutT + (size_t)E * E;
        u16* qkvb  = hb + (size_t)Bn * S * E;
        u16* vT    = qkvb + (size_t)S * N3;
        u16* attnb = vT + (size_t)H * 256 * S;
        u16* sc    = attnb + (size_t)S * E;

        int hc = (int)((ws_size - fixed) / per_head);
        if (hc > H) hc = H;
        while (H % hc) --hc;

        // one-time conversions/transposes
        cvt_kernel<<<dim3(2048), blk, 0, stream>>>(hidden, hb, (long)Bn * S * E / 8);
        transpose_kernel<float><<<dim3(N3 / 64, E / 64, 1), blk, 0, stream>>>(
            w_qkv, N3, 0, 0L, wqkvT, E, 0L);
        transpose_kernel<float><<<dim3(E / 64, E / 64, 1), blk, 0, stream>>>(
            w_out, E, 0, 0L, woutT, E, 0L);

        for (int b = 0; b < Bn; ++b) {
            // 1. QKV projection: bf16 [2048,4096] x [12288,4096]^T -> bf16 [2048,12288]
            gemm_bt<u16><<<dim3(N3 / BN, S / BM, 1), blk, 0, stream>>>(
                hb + (size_t)b * S * E, 0L, 0, E,
                wqkvT, 0L, 0, E,
                qkvb, 0L, N3, E, 0, 0);

            // 2. rotary (+ q *= 1/16)
            rotary_kernel<<<dim3(S), blk, 0, stream>>>(qkvb, pos + (size_t)b * S);

            // 3. V^T per head: [2048,256] -> [256,2048]
            transpose_kernel<u16><<<dim3(256 / 64, S / 64, H), blk, 0, stream>>>(
                qkvb, N3, 1, 0L, vT, S, (long)256 * S);

            // 4. attention, head-chunked
            for (int h0 = 0; h0 < H; h0 += hc) {
                gemm_bt<u16><<<dim3(S / BN, S / BM, hc), blk, 0, stream>>>(
                    qkvb, 0L, 1, N3,
                    qkvb, 0L, 1, N3,
                    sc, (long)S * S, S,
                    256, 1, h0);
                softmax_kernel<<<dim3(S, hc), blk, 0, stream>>>(sc);
                gemm_bt<u16><<<dim3(2, S / BM, hc), blk, 0, stream>>>(
                    sc, (long)S * S, 0, S,
                    vT + (size_t)h0 * 256 * S, (long)256 * S, 0, S,
                    attnb + (size_t)h0 * 256, 256L, E,
                    S, 2, h0);
            }

            // 5. output projection: bf16 x bf16^T -> f32
            gemm_bt<float><<<dim3(E / BN, S / BM, 1), blk, 0, stream>>>(
                attnb, 0L, 0, E,
                woutT, 0L, 0, E,
                out + (size_t)b * S * E, 0L, E, E, 0, 0);
        }
        return;
    }

    // ---------------- fallback: previous (verified) path ----------------
    u16* qkvb  = (u16*)d_ws;
    u16* attnb = qkvb + (size_t)S * N3;
    u16* sc    = attnb + (size_t)S * E;

    const size_t need_base = ((size_t)S * N3 + (size_t)S * E) * 2;
    int hc = 1;
    if (ws_size > need_base) {
        size_t avail = ws_size - need_base;
        hc = (int)(avail / per_head);
        if (hc < 1) hc = 1;
        if (hc > H) hc = H;
        while (H % hc) --hc;
    }

    for (int b = 0; b < Bn; ++b) {
        gemm_bf16<false><<<dim3(N3 / BN, S / BM, 1), blk, 0, stream>>>(
            hidden + (size_t)b * S * E, 0L, 0, E,
            w_qkv, 0L, 0, N3,
            qkvb, 0L, N3, E, 0, 0);

        rotary_kernel<<<dim3(S), blk, 0, stream>>>(qkvb, pos + (size_t)b * S);

        for (int h0 = 0; h0 < H; h0 += hc) {
            gemm_bf16<true><<<dim3(S / BN, S / BM, hc), blk, 0, stream>>>(
                qkvb, 0L, 1, N3,
                qkvb, 0L, 3, N3,
                sc, (long)S * S, S,
                256, 1, h0);
            softmax_kernel<<<dim3(S, hc), blk, 0, stream>>>(sc);
            gemm_bf16<false><<<dim3(2, S / BM, hc), blk, 0, stream>>>(
                sc, (long)S * S, 0, S,
                qkvb, 0L, 2, N3,
                attnb + (size_t)h0 * 256, 256L, E,
                S, 2, h0);
        }

        gemm_bf16<false><<<dim3(E / BN, S / BM, 1), blk, 0, stream>>>(
            attnb, 0L, 0, E,
            w_out, 0L, 0, E,
            out + (size_t)b * S * E, 0L, E, E, 0, 0);
    }
}

// Round 2
// 1464.011 us; speedup vs baseline: 1.5470x; 1.1184x over previous
//
#include <hip/hip_runtime.h>
#include <stdint.h>

typedef unsigned short u16;
typedef __bf16 bf16x8 __attribute__((ext_vector_type(8)));
typedef float f32x4 __attribute__((ext_vector_type(4)));

#define BM 128
#define BN 128
#define BK 32
#define SE 40  // fallback-path LDS row stride

__device__ __forceinline__ float bf2f(u16 u) {
    return __uint_as_float(((unsigned int)u) << 16);
}
__device__ __forceinline__ u16 f2bf(float f) {
    unsigned int x = __float_as_uint(f);
    return (u16)((x + 0x7fffu + ((x >> 16) & 1u)) >> 16);  // RNE (no NaN inputs in this pipeline)
}

__device__ __forceinline__ void ld8(const u16* p, u16* d) {
    *(uint4*)d = *(const uint4*)p;
}
__device__ __forceinline__ void ld8(const float* p, u16* d) {
    float4 a = *(const float4*)p;
    float4 b = *(const float4*)(p + 4);
    d[0] = f2bf(a.x); d[1] = f2bf(a.y); d[2] = f2bf(a.z); d[3] = f2bf(a.w);
    d[4] = f2bf(b.x); d[5] = f2bf(b.y); d[6] = f2bf(b.z); d[7] = f2bf(b.w);
}

__device__ __forceinline__ void stC(u16* p, float v)  { *p = f2bf(v); }
__device__ __forceinline__ void stC(float* p, float v){ *p = v; }

// async global->LDS, 16B per lane; LDS dest = wave-uniform base + lane*16 (HW rule)
__device__ __forceinline__ void gld_lds16(const u16* g, u16* l) {
    __builtin_amdgcn_global_load_lds(
        (__attribute__((address_space(1))) unsigned int*)(uintptr_t)(const void*)g,
        (__attribute__((address_space(3))) unsigned int*)(uintptr_t)(void*)l,
        16, 0, 0);
}

// ---------------------------------------------------------------------------
// 256x256 8-phase bf16 GEMM (T2+T3+T4+T5), B-transposed:
//   C[M,N] = A[M,K] * B^T ; A [M,K] (lda), B [N,K] (ldb), both bf16.
// 8 waves (512 thr). LDS 128 KiB: A: 2 tiles x 2 halves x [128][64]; B same at +64KiB.
// Per K-tile: 4 phases, each = one 128x128 output quadrant over K=64.
// Staging: 1 half-tile per phase (2 x global_load_lds dwordx4 per thread),
//   XOR chunk-swizzle on the GLOBAL source (LDS stays linear), counted vmcnt(4)
//   once per K-tile. Raw s_barrier + sched_barrier(0) pins (no vmcnt-0 drain).
// aMode/bMode/causal semantics as before (qkv head offsets, causal skip/limit).
// ---------------------------------------------------------------------------
template <typename TC>
__global__ __launch_bounds__(512, 2) void gemm256(
    const u16* __restrict__ A, long strideAz, int aMode, int lda,
    const u16* __restrict__ B, long strideBz, int bMode, int ldb,
    TC* __restrict__ C, long strideCz, int ldc,
    int K, int causal, int zBase)
{
    const int bx = blockIdx.x, by = blockIdx.y, bz = blockIdx.z;
    if (causal == 1 && bx > by) return;
    int kLen = K;
    if (causal == 2) { int kl = (by + 1) * 256; kLen = kl < K ? kl : K; }
    const int NT = kLen >> 6;   // all call sites give NT even, >= 4

    const int hz = bz + zBase;
    const long hoff = (long)((hz >> 2) * 3072 + (hz & 3) * 256);
    const u16* Ab = A + (aMode == 0 ? strideAz * bz : hoff);          // q at +0
    const u16* Bb = B + (bMode == 0 ? strideBz * bz : hoff + 2048);   // k at +2048
    TC* Cb = C + strideCz * bz;

    __shared__ __align__(16) u16 sm[65536];   // 128 KiB; A at 0, B at u16 32768

    const int tid  = threadIdx.x;
    const int lane = tid & 63;
    const int wave = tid >> 6;
    const int quad = lane >> 4;
    const int l16  = lane & 15;
    const int wqm  = wave >> 2;   // 0..1 : 64-row band within quadrant
    const int wqn  = wave & 3;    // 0..3 : 32-col band within quadrant
    const int rowA0 = by * 256;
    const int rowB0 = bx * 256;

    const int sr  = lane >> 3;            // staging row within 8-row group
    const int sc8 = ((lane & 7) ^ sr) * 8; // XOR-swizzled source chunk (T2, rule #21)

    f32x4 acc[2][4][2][2] = {};
    bf16x8 a_r[4][2], b_r[2][2];

// stage one 128x64 half-tile: LDS linear (global_load_lds), source pre-swizzled
#define STAGE(G, ld, gr0, kc, smbase) do { \
    _Pragma("unroll") \
    for (int c_ = 0; c_ < 2; ++c_) \
        gld_lds16((G) + (long)((gr0) + c_ * 64 + wave * 8 + sr) * (ld) + ((kc) + sc8), \
                  (smbase) + c_ * 4096 + wave * 512); \
} while (0)

// reads: un-swizzle with chunk ^ (row&7); 2-way bank conflicts max (free)
#define ARD(CUR, MH) do { \
    const u16* ab_ = &sm[(CUR) * 16384 + (MH) * 8192]; \
    _Pragma("unroll") for (int i_ = 0; i_ < 4; ++i_) { \
        const int lr_ = wqm * 64 + i_ * 16 + l16; \
        _Pragma("unroll") for (int k_ = 0; k_ < 2; ++k_) \
            a_r[i_][k_] = *(const bf16x8*)(ab_ + lr_ * 64 + (((k_ * 4 + quad) ^ (lr_ & 7)) * 8)); \
    } \
} while (0)

#define BRD(CUR, NH) do { \
    const u16* bb_ = &sm[32768 + (CUR) * 16384 + (NH) * 8192]; \
    _Pragma("unroll") for (int j_ = 0; j_ < 2; ++j_) { \
        const int lr_ = wqn * 32 + j_ * 16 + l16; \
        _Pragma("unroll") for (int k_ = 0; k_ < 2; ++k_) \
            b_r[j_][k_] = *(const bf16x8*)(bb_ + lr_ * 64 + (((k_ * 4 + quad) ^ (lr_ & 7)) * 8)); \
    } \
} while (0)

#define MFMAQ(MH, NH) do { \
    __builtin_amdgcn_s_setprio(1); \
    _Pragma("unroll") for (int i_ = 0; i_ < 4; ++i_) \
    _Pragma("unroll") for (int j_ = 0; j_ < 2; ++j_) \
    _Pragma("unroll") for (int k_ = 0; k_ < 2; ++k_) \
        acc[MH][i_][NH][j_] = __builtin_amdgcn_mfma_f32_16x16x32_bf16( \
            a_r[i_][k_], b_r[j_][k_], acc[MH][i_][NH][j_], 0, 0, 0); \
    __builtin_amdgcn_s_setprio(0); \
} while (0)

#define SB __builtin_amdgcn_sched_barrier(0)
#define BARA do { SB; __builtin_amdgcn_s_barrier(); \
                  asm volatile("s_waitcnt lgkmcnt(0)" ::: "memory"); SB; } while (0)
#define BARB do { SB; __builtin_amdgcn_s_barrier(); SB; } while (0)

    // prologue: tile0 all 4 halves + tile1 {Ah0,Bh0}; vmcnt(4) -> tile0 landed
    STAGE(Ab, lda, rowA0,       0, &sm[0]);
    STAGE(Bb, ldb, rowB0,       0, &sm[32768]);
    STAGE(Ab, lda, rowA0 + 128, 0, &sm[8192]);
    STAGE(Bb, ldb, rowB0 + 128, 0, &sm[32768 + 8192]);
    STAGE(Ab, lda, rowA0,      64, &sm[16384]);
    STAGE(Bb, ldb, rowB0,      64, &sm[32768 + 16384]);
    asm volatile("s_waitcnt vmcnt(4)" ::: "memory");
    SB; __builtin_amdgcn_s_barrier(); SB;

    // Window = 1 K-tile (4 phases). Stage stream per window T:
    //   p1: (T+1).Ah1   p2: (T+1).Bh1   p3: (T+2).Ah0   p4: (T+2).Bh0
    // WAR-safe: each slot's overwrite is issued >=1 barrier after its last read.
    // vmcnt(4) at p4 leaves exactly (T+2).{Ah0,Bh0} in flight; everything of
    // tile T+1 is guaranteed landed before the next window reads it.
#define WINDOW(CUR, T) do { \
    ARD(CUR, 0); BRD(CUR, 0); \
    if ((T) + 1 < NT) STAGE(Ab, lda, rowA0 + 128, ((T) + 1) * 64, &sm[(1 - (CUR)) * 16384 + 8192]); \
    BARA; MFMAQ(0, 0); BARB; \
    BRD(CUR, 1); \
    if ((T) + 1 < NT) STAGE(Bb, ldb, rowB0 + 128, ((T) + 1) * 64, &sm[32768 + (1 - (CUR)) * 16384 + 8192]); \
    BARA; MFMAQ(0, 1); BARB; \
    ARD(CUR, 1); BRD(CUR, 0); \
    if ((T) + 2 < NT) STAGE(Ab, lda, rowA0, ((T) + 2) * 64, &sm[(CUR) * 16384]); \
    BARA; MFMAQ(1, 0); BARB; \
    BRD(CUR, 1); \
    if ((T) + 2 < NT) { STAGE(Bb, ldb, rowB0, ((T) + 2) * 64, &sm[32768 + (CUR) * 16384]); \
                        asm volatile("s_waitcnt vmcnt(4)" ::: "memory"); } \
    else                asm volatile("s_waitcnt vmcnt(0)" ::: "memory"); \
    BARA; MFMAQ(1, 1); BARB; \
} while (0)

    for (int t = 0; t < NT; t += 2) { WINDOW(0, t); WINDOW(1, t + 1); }

#undef WINDOW
#undef STAGE
#undef ARD
#undef BRD
#undef MFMAQ
#undef SB
#undef BARA
#undef BARB

    #pragma unroll
    for (int mh = 0; mh < 2; ++mh)
    #pragma unroll
    for (int i = 0; i < 4; ++i) {
        const int r0 = rowA0 + mh * 128 + wqm * 64 + i * 16 + quad * 4;
        #pragma unroll
        for (int nh = 0; nh < 2; ++nh)
        #pragma unroll
        for (int j = 0; j < 2; ++j) {
            const int c = rowB0 + nh * 128 + wqn * 32 + j * 16 + l16;
            #pragma unroll
            for (int r = 0; r < 4; ++r)
                stC(&Cb[(long)(r0 + r) * ldc + c], acc[mh][i][nh][j][r]);
        }
    }
}

// f32 -> bf16 elementwise, 8 elems/thread
__global__ __launch_bounds__(256) void cvt_kernel(const float* __restrict__ in,
                                                  u16* __restrict__ out, long n8)
{
    long i = (long)blockIdx.x * 256 + threadIdx.x;
    const long stride = (long)gridDim.x * 256;
    for (; i < n8; i += stride) {
        const float* p = in + i * 8;
        u16 d[8];
        ld8(p, d);
        *(uint4*)(out + i * 8) = *(uint4*)d;
    }
}

// 64x64 tiled transpose -> bf16. in logical [R][C] (ldin), out [C][R] (ldout).
__device__ __forceinline__ void ld4(const float* p, u16* d) {
    float4 v = *(const float4*)p;
    d[0] = f2bf(v.x); d[1] = f2bf(v.y); d[2] = f2bf(v.z); d[3] = f2bf(v.w);
}
__device__ __forceinline__ void ld4(const u16* p, u16* d) {
    *(uint2*)d = *(const uint2*)p;
}

template <typename TIn>
__global__ __launch_bounds__(256) void transpose_kernel(
    const TIn* __restrict__ in, int ldin, int inMode, long inZ,
    u16* __restrict__ out, int ldout, long outZ)
{
    __shared__ u16 t[64][68];
    const int bx = blockIdx.x, by = blockIdx.y, bz = blockIdx.z;
    const TIn* inb = in + (inMode == 0 ? inZ * bz
                          : (long)((bz >> 2) * 3072 + 1024 + (bz & 3) * 256));
    u16* outb = out + outZ * bz;
    const int tid = threadIdx.x;
    const int r0 = by * 64;
    const int c0 = bx * 64;
    const int lr = tid >> 4;
    const int lc = (tid & 15) * 4;
    #pragma unroll
    for (int i = 0; i < 4; ++i) {
        u16 d[4];
        ld4(inb + (long)(r0 + lr + i * 16) * ldin + (c0 + lc), d);
        *(uint2*)(&t[lr + i * 16][lc]) = *(uint2*)d;
    }
    __syncthreads();
    const int oc  = tid >> 3;
    const int oro = (tid & 7) * 8;
    #pragma unroll
    for (int i = 0; i < 2; ++i) {
        u16 d[8];
        #pragma unroll
        for (int j = 0; j < 8; ++j) d[j] = t[oro + j][oc + i * 32];
        *(uint4*)(outb + (long)(c0 + oc + i * 32) * ldout + (r0 + oro)) = *(uint4*)d;
    }
}

// ---------------------------------------------------------------------------
// FALLBACK generic GEMM — used only if workspace is too small.
// ---------------------------------------------------------------------------
template <bool BT, typename TA, typename TB, typename TC>
__global__ __launch_bounds__(256) void gemm_bf16(
    const TA* __restrict__ A, long strideAz, int aMode, int lda,
    const TB* __restrict__ B, long strideBz, int bMode, int ldb,
    TC* __restrict__ C, long strideCz, int ldc,
    int K, int causal, int zBase)
{
    const int bx = blockIdx.x, by = blockIdx.y, bz = blockIdx.z;
    if (causal == 1 && bx > by) return;
    int kLen = K;
    if (causal == 2) { int kl = (by + 1) * BM; kLen = kl < K ? kl : K; }

    const int hz = bz + zBase;
    const long hoff = (long)((hz >> 2) * 3072 + (hz & 3) * 256);
    const TA* Ab = A + (aMode == 0 ? strideAz * bz : hoff + (long)(aMode - 1) * 1024);
    const TB* Bb = B + (bMode == 0 ? strideBz * bz : hoff + (long)(bMode - 1) * 1024);
    TC* Cb = C + strideCz * bz;

    __shared__ __align__(16) u16 As[BM][SE];
    __shared__ __align__(16) u16 Bs[BN][SE];

    const int tid  = threadIdx.x;
    const int lane = tid & 63;
    const int wave = tid >> 6;
    const int quad = lane >> 4;
    const int l16  = lane & 15;
    const int mBase = (wave >> 1) * 64;
    const int nBase = (wave & 1) * 64;

    const int row0 = by * BM;
    const int col0 = bx * BN;

    const int ar = tid >> 2;
    const int ac = (tid & 3) * 8;
    const int bk = tid & 15;
    const int bg = tid >> 4;

    f32x4 acc[4][4] = {};

    for (int k0 = 0; k0 < kLen; k0 += BK) {
        {
            u16 t0[8], t1[8];
            ld8(Ab + (long)(row0 + ar) * lda + (k0 + ac), t0);
            ld8(Ab + (long)(row0 + ar + 64) * lda + (k0 + ac), t1);
            *(uint4*)(&As[ar][ac])      = *(uint4*)t0;
            *(uint4*)(&As[ar + 64][ac]) = *(uint4*)t1;
        }
        if (BT) {
            u16 t0[8], t1[8];
            ld8(Bb + (long)(col0 + ar) * ldb + (k0 + ac), t0);
            ld8(Bb + (long)(col0 + ar + 64) * ldb + (k0 + ac), t1);
            *(uint4*)(&Bs[ar][ac])      = *(uint4*)t0;
            *(uint4*)(&Bs[ar + 64][ac]) = *(uint4*)t1;
        } else {
            u16 s0[8], s1[8];
            ld8(Bb + (long)(k0 + bk) * ldb + (col0 + bg * 8), s0);
            ld8(Bb + (long)(k0 + bk + 16) * ldb + (col0 + bg * 8), s1);
            #pragma unroll
            for (int j = 0; j < 8; ++j) {
                const int jj = (j + 2 * bg) & 7;
                Bs[bg * 8 + jj][bk]      = s0[jj];
                Bs[bg * 8 + jj][bk + 16] = s1[jj];
            }
        }
        __syncthreads();

        bf16x8 af[4], bfr[4];
        #pragma unroll
        for (int i = 0; i < 4; ++i)
            af[i] = *(const bf16x8*)(&As[mBase + 16 * i + l16][quad * 8]);
        #pragma unroll
        for (int j = 0; j < 4; ++j)
            bfr[j] = *(const bf16x8*)(&Bs[nBase + 16 * j + l16][quad * 8]);
        #pragma unroll
        for (int i = 0; i < 4; ++i)
            #pragma unroll
            for (int j = 0; j < 4; ++j)
                acc[i][j] = __builtin_amdgcn_mfma_f32_16x16x32_bf16(af[i], bfr[j], acc[i][j], 0, 0, 0);
        __syncthreads();
    }

    #pragma unroll
    for (int i = 0; i < 4; ++i) {
        const int r0 = row0 + mBase + 16 * i + quad * 4;
        #pragma unroll
        for (int j = 0; j < 4; ++j) {
            const int c = col0 + nBase + 16 * j + l16;
            #pragma unroll
            for (int r = 0; r < 4; ++r)
                stC(&Cb[(long)(r0 + r) * ldc + c], acc[i][j][r]);
        }
    }
}

// In-place GPT-J rotary on q,k + fold 1/sqrt(D)=1/16 into q.
__global__ __launch_bounds__(256) void rotary_kernel(u16* __restrict__ qkv,
                                                     const int* __restrict__ pos_ids)
{
    const long bs = blockIdx.x;
    const float pos = (float)pos_ids[bs];
    u16* row = qkv + bs * 12288;
    for (int idx = threadIdx.x; idx < 16 * 224; idx += 256) {
        const int h = idx / 224;
        const int r = idx - h * 224;
        const int base = (h >> 2) * 3072 + (h & 3) * 256;
        if (r < 32) {
            const float invf = powf(10000.0f, (-2.0f * (float)r) * (1.0f / 64.0f));
            float s, c;
            sincosf(pos * invf, &s, &c);
            const int d0 = base + 2 * r;
            const int k0 = d0 + 2048;
            float q0 = bf2f(row[d0]), q1 = bf2f(row[d0 + 1]);
            float ka = bf2f(row[k0]), kb = bf2f(row[k0 + 1]);
            row[d0]     = f2bf((q0 * c - q1 * s) * 0.0625f);
            row[d0 + 1] = f2bf((q1 * c + q0 * s) * 0.0625f);
            row[k0]     = f2bf(ka * c - kb * s);
            row[k0 + 1] = f2bf(kb * c + ka * s);
        } else {
            const int d = base + 64 + (r - 32);
            row[d] = f2bf(bf2f(row[d]) * 0.0625f);
        }
    }
}

// Causal row softmax
__global__ __launch_bounds__(256) void softmax_kernel(u16* __restrict__ scores)
{
    const int qi = blockIdx.x;
    const int h  = blockIdx.y;
    u16* row = scores + ((long)h * 2048 + qi) * 2048;
    const int tid = threadIdx.x;
    const int n = qi + 1;

    float vals[8];
    float lmax = -3.0e38f;
    #pragma unroll
    for (int i = 0; i < 8; ++i) {
        const int j = tid + i * 256;
        const float v = (j < n) ? bf2f(row[j]) : -3.0e38f;
        vals[i] = v;
        lmax = fmaxf(lmax, v);
    }
    __shared__ float red[4];
    #pragma unroll
    for (int off = 32; off > 0; off >>= 1) lmax = fmaxf(lmax, __shfl_down(lmax, off));
    if ((tid & 63) == 0) red[tid >> 6] = lmax;
    __syncthreads();
    lmax = fmaxf(fmaxf(red[0], red[1]), fmaxf(red[2], red[3]));

    float lsum = 0.f;
    #pragma unroll
    for (int i = 0; i < 8; ++i) {
        const int j = tid + i * 256;
        const float e = (j < n) ? expf(vals[i] - lmax) : 0.f;
        vals[i] = e;
        lsum += e;
    }
    #pragma unroll
    for (int off = 32; off > 0; off >>= 1) lsum += __shfl_down(lsum, off);
    __syncthreads();
    if ((tid & 63) == 0) red[tid >> 6] = lsum;
    __syncthreads();
    lsum = red[0] + red[1] + red[2] + red[3];
    const float inv = 1.0f / lsum;
    #pragma unroll
    for (int i = 0; i < 8; ++i)
        row[tid + i * 256] = f2bf(vals[i] * inv);
}

extern "C" void kernel_launch(void* const* d_in, const int* in_sizes, int n_in,
                              void* d_out, int out_size, void* d_ws, size_t ws_size,
                              hipStream_t stream)
{
    const float* hidden = (const float*)d_in[0];
    const float* w_qkv  = (const float*)d_in[1];
    const float* w_out  = (const float*)d_in[2];
    const int*   pos    = (const int*)d_in[3];
    float* out = (float*)d_out;

    const int Bn = 2, S = 2048, E = 4096, H = 16;
    const int N3 = 3 * E;  // 12288
    const size_t per_head = (size_t)S * S * 2;  // 8 MiB

    dim3 blk(256);
    dim3 blk2(512);

    // ---------------- fast path layout (bf16, bytes) ----------------
    const size_t fixed =
        (size_t)N3 * E * 2 +        // wqkvT
        (size_t)E * E * 2 +         // woutT
        (size_t)Bn * S * E * 2 +    // hb
        (size_t)S * N3 * 2 +        // qkvb
        (size_t)H * 256 * S * 2 +   // vT
        (size_t)S * E * 2;          // attnb

    if (ws_size >= fixed + per_head) {
        u16* wqkvT = (u16*)d_ws;
        u16* woutT = wqkvT + (size_t)N3 * E;
        u16* hb    = woutT + (size_t)E * E;
        u16* qkvb  = hb + (size_t)Bn * S * E;
        u16* vT    = qkvb + (size_t)S * N3;
        u16* attnb = vT + (size_t)H * 256 * S;
        u16* sc    = attnb + (size_t)S * E;

        int hc = (int)((ws_size - fixed) / per_head);
        if (hc > H) hc = H;
        while (H % hc) --hc;

        // one-time conversions/transposes
        cvt_kernel<<<dim3(2048), blk, 0, stream>>>(hidden, hb, (long)Bn * S * E / 8);
        transpose_kernel<float><<<dim3(N3 / 64, E / 64, 1), blk, 0, stream>>>(
            w_qkv, N3, 0, 0L, wqkvT, E, 0L);
        transpose_kernel<float><<<dim3(E / 64, E / 64, 1), blk, 0, stream>>>(
            w_out, E, 0, 0L, woutT, E, 0L);

        for (int b = 0; b < Bn; ++b) {
            // 1. QKV projection: bf16 [2048,4096] x [12288,4096]^T -> bf16
            gemm256<u16><<<dim3(N3 / 256, S / 256, 1), blk2, 0, stream>>>(
                hb + (size_t)b * S * E, 0L, 0, E,
                wqkvT, 0L, 0, E,
                qkvb, 0L, N3, E, 0, 0);

            // 2. rotary (+ q *= 1/16)
            rotary_kernel<<<dim3(S), blk, 0, stream>>>(qkvb, pos + (size_t)b * S);

            // 3. V^T per head: [2048,256] -> [256,2048]
            transpose_kernel<u16><<<dim3(256 / 64, S / 64, H), blk, 0, stream>>>(
                qkvb, N3, 1, 0L, vT, S, (long)256 * S);

            // 4. attention, head-chunked
            for (int h0 = 0; h0 < H; h0 += hc) {
                gemm256<u16><<<dim3(S / 256, S / 256, hc), blk2, 0, stream>>>(
                    qkvb, 0L, 1, N3,
                    qkvb, 0L, 1, N3,
                    sc, (long)S * S, S,
                    256, 1, h0);
                softmax_kernel<<<dim3(S, hc), blk, 0, stream>>>(sc);
                gemm256<u16><<<dim3(1, S / 256, hc), blk2, 0, stream>>>(
                    sc, (long)S * S, 0, S,
                    vT + (size_t)h0 * 256 * S, (long)256 * S, 0, S,
                    attnb + (size_t)h0 * 256, 256L, E,
                    S, 2, h0);
            }

            // 5. output projection: bf16 x bf16^T -> f32
            gemm256<float><<<dim3(E / 256, S / 256, 1), blk2, 0, stream>>>(
                attnb, 0L, 0, E,
                woutT, 0L, 0, E,
                out + (size_t)b * S * E, 0L, E, E, 0, 0);
        }
        return;
    }

    // ---------------- fallback: register-staged path ----------------
    u16* qkvb  = (u16*)d_ws;
    u16* attnb = qkvb + (size_t)S * N3;
    u16* sc    = attnb + (size_t)S * E;

    const size_t need_base = ((size_t)S * N3 + (size_t)S * E) * 2;
    int hc = 1;
    if (ws_size > need_base) {
        size_t avail = ws_size - need_base;
        hc = (int)(avail / per_head);
        if (hc < 1) hc = 1;
        if (hc > H) hc = H;
        while (H % hc) --hc;
    }

    for (int b = 0; b < Bn; ++b) {
        gemm_bf16<false><<<dim3(N3 / BN, S / BM, 1), blk, 0, stream>>>(
            hidden + (size_t)b * S * E, 0L, 0, E,
            w_qkv, 0L, 0, N3,
            qkvb, 0L, N3, E, 0, 0);

        rotary_kernel<<<dim3(S), blk, 0, stream>>>(qkvb, pos + (size_t)b * S);

        for (int h0 = 0; h0 < H; h0 += hc) {
            gemm_bf16<true><<<dim3(S / BN, S / BM, hc), blk, 0, stream>>>(
                qkvb, 0L, 1, N3,
                qkvb, 0L, 3, N3,
                sc, (long)S * S, S,
                256, 1, h0);
            softmax_kernel<<<dim3(S, hc), blk, 0, stream>>>(sc);
            gemm_bf16<false><<<dim3(2, S / BM, hc), blk, 0, stream>>>(
                sc, (long)S * S, 0, S,
                qkvb, 0L, 2, N3,
                attnb + (size_t)h0 * 256, 256L, E,
                S, 2, h0);
        }

        gemm_bf16<false><<<dim3(E / BN, S / BM, 1), blk, 0, stream>>>(
            attnb, 0L, 0, E,
            w_out, 0L, 0, E,
            out + (size_t)b * S * E, 0L, E, E, 0, 0);
    }
}

// Round 3
// 1165.145 us; speedup vs baseline: 1.9438x; 1.2565x over previous
//
#include <hip/hip_runtime.h>
#include <stdint.h>

typedef unsigned short u16;
typedef __bf16 bf16x8 __attribute__((ext_vector_type(8)));
typedef float f32x4 __attribute__((ext_vector_type(4)));

#define BM 128
#define BN 128
#define BK 32
#define SE 40  // fallback-path LDS row stride

__device__ __forceinline__ float bf2f(u16 u) {
    return __uint_as_float(((unsigned int)u) << 16);
}
__device__ __forceinline__ u16 f2bf(float f) {
    unsigned int x = __float_as_uint(f);
    return (u16)((x + 0x7fffu + ((x >> 16) & 1u)) >> 16);  // RNE (no NaN inputs in this pipeline)
}

__device__ __forceinline__ void ld8(const u16* p, u16* d) {
    *(uint4*)d = *(const uint4*)p;
}
__device__ __forceinline__ void ld8(const float* p, u16* d) {
    float4 a = *(const float4*)p;
    float4 b = *(const float4*)(p + 4);
    d[0] = f2bf(a.x); d[1] = f2bf(a.y); d[2] = f2bf(a.z); d[3] = f2bf(a.w);
    d[4] = f2bf(b.x); d[5] = f2bf(b.y); d[6] = f2bf(b.z); d[7] = f2bf(b.w);
}

__device__ __forceinline__ void stC(u16* p, float v)  { *p = f2bf(v); }
__device__ __forceinline__ void stC(float* p, float v){ *p = v; }

// async global->LDS, 16B per lane; LDS dest = wave-uniform base + lane*16 (HW rule)
__device__ __forceinline__ void gld_lds16(const u16* g, u16* l) {
    __builtin_amdgcn_global_load_lds(
        (__attribute__((address_space(1))) unsigned int*)(uintptr_t)(const void*)g,
        (__attribute__((address_space(3))) unsigned int*)(uintptr_t)(void*)l,
        16, 0, 0);
}

// z-offset modes (hz = bz + zBase):
//   0: stride * bz                      (chunk-local buffer)
//   1: qkv: (hz>>4)*stride + (h>>2)*3072 + (h&3)*256, h = hz&15  (caller adds +2048 for K)
//   3: stride * hz                      (global-z linear)
//   4: (hz>>4)*stride + (hz&15)*256     (attn output head column)
__device__ __forceinline__ long zoff(int mode, long stride, int hz, int bz) {
    if (mode == 0) return stride * (long)bz;
    if (mode == 1) { int h = hz & 15; return (long)(hz >> 4) * stride + (h >> 2) * 3072 + (h & 3) * 256; }
    if (mode == 3) return stride * (long)hz;
    return (long)(hz >> 4) * stride + (long)(hz & 15) * 256;
}

// ---------------------------------------------------------------------------
// 256x256 8-phase bf16 GEMM (T2+T3+T4+T5), B-transposed:
//   C[M,N] = A[M,K] * B^T ; A [M,K] (lda), B [N,K] (ldb), both bf16.
// 8 waves (512 thr). LDS 128 KiB: A: 2 tiles x 2 halves x [128][64]; B at +64KiB.
// Per K-tile: 4 phases = output quadrants (0,0),(0,1),(1,0),(1,1) over K=64.
// a_r single-buffered over M-halves, b_r double-buffered over N-halves ->
// 24 ds_read_b128 per K-tile (minimum). Staging: 1 half-tile per phase via
// global_load_lds dwordx4, XOR chunk-swizzle on GLOBAL source (LDS linear),
// counted vmcnt(4) once per K-tile. Raw s_barrier + sched_barrier(0) pins.
// causal: 0 none; 1 skip blocks bx>by; 2 kLen=(by+1)*256.
// ---------------------------------------------------------------------------
template <typename TC>
__global__ __launch_bounds__(512, 2) void gemm256(
    const u16* __restrict__ A, long strideAz, int aMode, int lda,
    const u16* __restrict__ B, long strideBz, int bMode, int ldb,
    TC* __restrict__ C, long strideCz, int cMode, int ldc,
    int K, int causal, int zBase)
{
    const int bx = blockIdx.x, by = blockIdx.y, bz = blockIdx.z;
    if (causal == 1 && bx > by) return;
    int kLen = K;
    if (causal == 2) { int kl = (by + 1) * 256; kLen = kl < K ? kl : K; }
    const int NT = kLen >> 6;   // all call sites give NT even, >= 4

    const int hz = bz + zBase;
    const u16* Ab = A + zoff(aMode, strideAz, hz, bz);
    const u16* Bb = B + zoff(bMode, strideBz, hz, bz);
    TC* Cb = C + zoff(cMode, strideCz, hz, bz);

    __shared__ __align__(16) u16 sm[65536];   // 128 KiB; A at 0, B at u16 32768

    const int tid  = threadIdx.x;
    const int lane = tid & 63;
    const int wave = tid >> 6;
    const int quad = lane >> 4;
    const int l16  = lane & 15;
    const int wqm  = wave >> 2;   // 0..1 : 64-row band within quadrant
    const int wqn  = wave & 3;    // 0..3 : 32-col band within quadrant
    const int rowA0 = by * 256;
    const int rowB0 = bx * 256;

    const int sr  = lane >> 3;             // staging row within 8-row group
    const int sc8 = ((lane & 7) ^ sr) * 8; // XOR-swizzled source chunk (T2, rule #21)

    f32x4 acc[2][4][2][2] = {};
    bf16x8 a_r[4][2], b_r[2][2][2];

// stage one 128x64 half-tile: LDS linear (global_load_lds), source pre-swizzled
#define STAGE(G, ld, gr0, kc, smbase) do { \
    _Pragma("unroll") \
    for (int c_ = 0; c_ < 2; ++c_) \
        gld_lds16((G) + (long)((gr0) + c_ * 64 + wave * 8 + sr) * (ld) + ((kc) + sc8), \
                  (smbase) + c_ * 4096 + wave * 512); \
} while (0)

// reads: un-swizzle with chunk ^ (row&7); 2-way bank conflicts max (free)
#define ARD(CUR, MH) do { \
    const u16* ab_ = &sm[(CUR) * 16384 + (MH) * 8192]; \
    _Pragma("unroll") for (int i_ = 0; i_ < 4; ++i_) { \
        const int lr_ = wqm * 64 + i_ * 16 + l16; \
        _Pragma("unroll") for (int k_ = 0; k_ < 2; ++k_) \
            a_r[i_][k_] = *(const bf16x8*)(ab_ + lr_ * 64 + (((k_ * 4 + quad) ^ (lr_ & 7)) * 8)); \
    } \
} while (0)

#define BRD(CUR, NH) do { \
    const u16* bb_ = &sm[32768 + (CUR) * 16384 + (NH) * 8192]; \
    _Pragma("unroll") for (int j_ = 0; j_ < 2; ++j_) { \
        const int lr_ = wqn * 32 + j_ * 16 + l16; \
        _Pragma("unroll") for (int k_ = 0; k_ < 2; ++k_) \
            b_r[NH][j_][k_] = *(const bf16x8*)(bb_ + lr_ * 64 + (((k_ * 4 + quad) ^ (lr_ & 7)) * 8)); \
    } \
} while (0)

#define MFMAQ(MH, NH) do { \
    __builtin_amdgcn_s_setprio(1); \
    _Pragma("unroll") for (int i_ = 0; i_ < 4; ++i_) \
    _Pragma("unroll") for (int j_ = 0; j_ < 2; ++j_) \
    _Pragma("unroll") for (int k_ = 0; k_ < 2; ++k_) \
        acc[MH][i_][NH][j_] = __builtin_amdgcn_mfma_f32_16x16x32_bf16( \
            a_r[i_][k_], b_r[NH][j_][k_], acc[MH][i_][NH][j_], 0, 0, 0); \
    __builtin_amdgcn_s_setprio(0); \
} while (0)

#define SB __builtin_amdgcn_sched_barrier(0)
#define BARA do { SB; __builtin_amdgcn_s_barrier(); \
                  asm volatile("s_waitcnt lgkmcnt(0)" ::: "memory"); SB; } while (0)
#define BARB do { SB; __builtin_amdgcn_s_barrier(); SB; } while (0)

    // prologue: tile0 all 4 halves + tile1 {Ah0,Bh0}; vmcnt(4) -> tile0 landed
    STAGE(Ab, lda, rowA0,       0, &sm[0]);
    STAGE(Bb, ldb, rowB0,       0, &sm[32768]);
    STAGE(Ab, lda, rowA0 + 128, 0, &sm[8192]);
    STAGE(Bb, ldb, rowB0 + 128, 0, &sm[32768 + 8192]);
    STAGE(Ab, lda, rowA0,      64, &sm[16384]);
    STAGE(Bb, ldb, rowB0,      64, &sm[32768 + 16384]);
    asm volatile("s_waitcnt vmcnt(4)" ::: "memory");
    SB; __builtin_amdgcn_s_barrier(); SB;

    // Window = 1 K-tile (4 phases). Stage stream per window T:
    //   p1: (T+1).Ah1   p2: (T+1).Bh1   p3: (T+2).Ah0   p4: (T+2).Bh0
    // WAR-safe: each slot's overwrite is issued >=1 barrier after its last read
    // completed (reads complete at that phase's lgkmcnt(0), >=2 barriers prior).
    // vmcnt(4) at p4 leaves exactly (T+2).{Ah0,Bh0} in flight.
#define WINDOW(CUR, T) do { \
    ARD(CUR, 0); BRD(CUR, 0); \
    if ((T) + 1 < NT) STAGE(Ab, lda, rowA0 + 128, ((T) + 1) * 64, &sm[(1 - (CUR)) * 16384 + 8192]); \
    BARA; MFMAQ(0, 0); BARB; \
    BRD(CUR, 1); \
    if ((T) + 1 < NT) STAGE(Bb, ldb, rowB0 + 128, ((T) + 1) * 64, &sm[32768 + (1 - (CUR)) * 16384 + 8192]); \
    BARA; MFMAQ(0, 1); BARB; \
    ARD(CUR, 1); \
    if ((T) + 2 < NT) STAGE(Ab, lda, rowA0, ((T) + 2) * 64, &sm[(CUR) * 16384]); \
    BARA; MFMAQ(1, 0); BARB; \
    if ((T) + 2 < NT) { STAGE(Bb, ldb, rowB0, ((T) + 2) * 64, &sm[32768 + (CUR) * 16384]); \
                        asm volatile("s_waitcnt vmcnt(4)" ::: "memory"); } \
    else                asm volatile("s_waitcnt vmcnt(0)" ::: "memory"); \
    BARA; MFMAQ(1, 1); BARB; \
} while (0)

    for (int t = 0; t < NT; t += 2) { WINDOW(0, t); WINDOW(1, t + 1); }

#undef WINDOW
#undef STAGE
#undef ARD
#undef BRD
#undef MFMAQ
#undef SB
#undef BARA
#undef BARB

    #pragma unroll
    for (int mh = 0; mh < 2; ++mh)
    #pragma unroll
    for (int i = 0; i < 4; ++i) {
        const int r0 = rowA0 + mh * 128 + wqm * 64 + i * 16 + quad * 4;
        #pragma unroll
        for (int nh = 0; nh < 2; ++nh)
        #pragma unroll
        for (int j = 0; j < 2; ++j) {
            const int c = rowB0 + nh * 128 + wqn * 32 + j * 16 + l16;
            #pragma unroll
            for (int r = 0; r < 4; ++r)
                stC(&Cb[(long)(r0 + r) * ldc + c], acc[mh][i][nh][j][r]);
        }
    }
}

// f32 -> bf16 elementwise, 8 elems/thread
__global__ __launch_bounds__(256) void cvt_kernel(const float* __restrict__ in,
                                                  u16* __restrict__ out, long n8)
{
    long i = (long)blockIdx.x * 256 + threadIdx.x;
    const long stride = (long)gridDim.x * 256;
    for (; i < n8; i += stride) {
        const float* p = in + i * 8;
        u16 d[8];
        ld8(p, d);
        *(uint4*)(out + i * 8) = *(uint4*)d;
    }
}

// 64x64 tiled transpose -> bf16. in logical [R][C] (ldin), out [C][R] (ldout).
// inMode 0: in + inZ*bz ; inMode 1: in + (bz>>4)*inZ + qkv V-head offset(bz&15)
__device__ __forceinline__ void ld4(const float* p, u16* d) {
    float4 v = *(const float4*)p;
    d[0] = f2bf(v.x); d[1] = f2bf(v.y); d[2] = f2bf(v.z); d[3] = f2bf(v.w);
}
__device__ __forceinline__ void ld4(const u16* p, u16* d) {
    *(uint2*)d = *(const uint2*)p;
}

template <typename TIn>
__global__ __launch_bounds__(256) void transpose_kernel(
    const TIn* __restrict__ in, int ldin, int inMode, long inZ,
    u16* __restrict__ out, int ldout, long outZ)
{
    __shared__ u16 t[64][68];
    const int bx = blockIdx.x, by = blockIdx.y, bz = blockIdx.z;
    const int h = bz & 15;
    const TIn* inb = in + (inMode == 0 ? inZ * bz
                          : (long)(bz >> 4) * inZ + (long)((h >> 2) * 3072 + 1024 + (h & 3) * 256));
    u16* outb = out + outZ * bz;
    const int tid = threadIdx.x;
    const int r0 = by * 64;
    const int c0 = bx * 64;
    const int lr = tid >> 4;
    const int lc = (tid & 15) * 4;
    #pragma unroll
    for (int i = 0; i < 4; ++i) {
        u16 d[4];
        ld4(inb + (long)(r0 + lr + i * 16) * ldin + (c0 + lc), d);
        *(uint2*)(&t[lr + i * 16][lc]) = *(uint2*)d;
    }
    __syncthreads();
    const int oc  = tid >> 3;
    const int oro = (tid & 7) * 8;
    #pragma unroll
    for (int i = 0; i < 2; ++i) {
        u16 d[8];
        #pragma unroll
        for (int j = 0; j < 8; ++j) d[j] = t[oro + j][oc + i * 32];
        *(uint4*)(outb + (long)(c0 + oc + i * 32) * ldout + (r0 + oro)) = *(uint4*)d;
    }
}

// ---------------------------------------------------------------------------
// FALLBACK generic GEMM — used only if workspace is too small.
// ---------------------------------------------------------------------------
template <bool BT, typename TA, typename TB, typename TC>
__global__ __launch_bounds__(256) void gemm_bf16(
    const TA* __restrict__ A, long strideAz, int aMode, int lda,
    const TB* __restrict__ B, long strideBz, int bMode, int ldb,
    TC* __restrict__ C, long strideCz, int ldc,
    int K, int causal, int zBase)
{
    const int bx = blockIdx.x, by = blockIdx.y, bz = blockIdx.z;
    if (causal == 1 && bx > by) return;
    int kLen = K;
    if (causal == 2) { int kl = (by + 1) * BM; kLen = kl < K ? kl : K; }

    const int hz = bz + zBase;
    const long hoff = (long)((hz >> 2) * 3072 + (hz & 3) * 256);
    const TA* Ab = A + (aMode == 0 ? strideAz * bz : hoff + (long)(aMode - 1) * 1024);
    const TB* Bb = B + (bMode == 0 ? strideBz * bz : hoff + (long)(bMode - 1) * 1024);
    TC* Cb = C + strideCz * bz;

    __shared__ __align__(16) u16 As[BM][SE];
    __shared__ __align__(16) u16 Bs[BN][SE];

    const int tid  = threadIdx.x;
    const int lane = tid & 63;
    const int wave = tid >> 6;
    const int quad = lane >> 4;
    const int l16  = lane & 15;
    const int mBase = (wave >> 1) * 64;
    const int nBase = (wave & 1) * 64;

    const int row0 = by * BM;
    const int col0 = bx * BN;

    const int ar = tid >> 2;
    const int ac = (tid & 3) * 8;
    const int bk = tid & 15;
    const int bg = tid >> 4;

    f32x4 acc[4][4] = {};

    for (int k0 = 0; k0 < kLen; k0 += BK) {
        {
            u16 t0[8], t1[8];
            ld8(Ab + (long)(row0 + ar) * lda + (k0 + ac), t0);
            ld8(Ab + (long)(row0 + ar + 64) * lda + (k0 + ac), t1);
            *(uint4*)(&As[ar][ac])      = *(uint4*)t0;
            *(uint4*)(&As[ar + 64][ac]) = *(uint4*)t1;
        }
        if (BT) {
            u16 t0[8], t1[8];
            ld8(Bb + (long)(col0 + ar) * ldb + (k0 + ac), t0);
            ld8(Bb + (long)(col0 + ar + 64) * ldb + (k0 + ac), t1);
            *(uint4*)(&Bs[ar][ac])      = *(uint4*)t0;
            *(uint4*)(&Bs[ar + 64][ac]) = *(uint4*)t1;
        } else {
            u16 s0[8], s1[8];
            ld8(Bb + (long)(k0 + bk) * ldb + (col0 + bg * 8), s0);
            ld8(Bb + (long)(k0 + bk + 16) * ldb + (col0 + bg * 8), s1);
            #pragma unroll
            for (int j = 0; j < 8; ++j) {
                const int jj = (j + 2 * bg) & 7;
                Bs[bg * 8 + jj][bk]      = s0[jj];
                Bs[bg * 8 + jj][bk + 16] = s1[jj];
            }
        }
        __syncthreads();

        bf16x8 af[4], bfr[4];
        #pragma unroll
        for (int i = 0; i < 4; ++i)
            af[i] = *(const bf16x8*)(&As[mBase + 16 * i + l16][quad * 8]);
        #pragma unroll
        for (int j = 0; j < 4; ++j)
            bfr[j] = *(const bf16x8*)(&Bs[nBase + 16 * j + l16][quad * 8]);
        #pragma unroll
        for (int i = 0; i < 4; ++i)
            #pragma unroll
            for (int j = 0; j < 4; ++j)
                acc[i][j] = __builtin_amdgcn_mfma_f32_16x16x32_bf16(af[i], bfr[j], acc[i][j], 0, 0, 0);
        __syncthreads();
    }

    #pragma unroll
    for (int i = 0; i < 4; ++i) {
        const int r0 = row0 + mBase + 16 * i + quad * 4;
        #pragma unroll
        for (int j = 0; j < 4; ++j) {
            const int c = col0 + nBase + 16 * j + l16;
            #pragma unroll
            for (int r = 0; r < 4; ++r)
                stC(&Cb[(long)(r0 + r) * ldc + c], acc[i][j][r]);
        }
    }
}

// In-place GPT-J rotary on q,k + fold 1/sqrt(D)=1/16 into q. bs spans batches.
__global__ __launch_bounds__(256) void rotary_kernel(u16* __restrict__ qkv,
                                                     const int* __restrict__ pos_ids)
{
    const long bs = blockIdx.x;
    const float pos = (float)pos_ids[bs];
    u16* row = qkv + bs * 12288;
    for (int idx = threadIdx.x; idx < 16 * 224; idx += 256) {
        const int h = idx / 224;
        const int r = idx - h * 224;
        const int base = (h >> 2) * 3072 + (h & 3) * 256;
        if (r < 32) {
            const float invf = powf(10000.0f, (-2.0f * (float)r) * (1.0f / 64.0f));
            float s, c;
            sincosf(pos * invf, &s, &c);
            const int d0 = base + 2 * r;
            const int k0 = d0 + 2048;
            float q0 = bf2f(row[d0]), q1 = bf2f(row[d0 + 1]);
            float ka = bf2f(row[k0]), kb = bf2f(row[k0 + 1]);
            row[d0]     = f2bf((q0 * c - q1 * s) * 0.0625f);
            row[d0 + 1] = f2bf((q1 * c + q0 * s) * 0.0625f);
            row[k0]     = f2bf(ka * c - kb * s);
            row[k0 + 1] = f2bf(kb * c + ka * s);
        } else {
            const int d = base + 64 + (r - 32);
            row[d] = f2bf(bf2f(row[d]) * 0.0625f);
        }
    }
}

// Causal row softmax; only touches the 256-chunks PV will read (j < ceil(n/256)*256).
__global__ __launch_bounds__(256) void softmax_kernel(u16* __restrict__ scores)
{
    const int qi = blockIdx.x;
    const int h  = blockIdx.y;
    u16* row = scores + ((long)h * 2048 + qi) * 2048;
    const int tid = threadIdx.x;
    const int n = qi + 1;
    const int nc = (qi >> 8) + 1;   // 256-chunks PV reads

    float vals[8];
    float lmax = -3.0e38f;
    #pragma unroll
    for (int i = 0; i < 8; ++i) {
        if (i < nc) {
            const int j = tid + i * 256;
            const float v = (j < n) ? bf2f(row[j]) : -3.0e38f;
            vals[i] = v;
            lmax = fmaxf(lmax, v);
        }
    }
    __shared__ float red[4];
    #pragma unroll
    for (int off = 32; off > 0; off >>= 1) lmax = fmaxf(lmax, __shfl_down(lmax, off));
    if ((tid & 63) == 0) red[tid >> 6] = lmax;
    __syncthreads();
    lmax = fmaxf(fmaxf(red[0], red[1]), fmaxf(red[2], red[3]));

    float lsum = 0.f;
    #pragma unroll
    for (int i = 0; i < 8; ++i) {
        if (i < nc) {
            const int j = tid + i * 256;
            const float e = (j < n) ? expf(vals[i] - lmax) : 0.f;
            vals[i] = e;
            lsum += e;
        }
    }
    #pragma unroll
    for (int off = 32; off > 0; off >>= 1) lsum += __shfl_down(lsum, off);
    __syncthreads();
    if ((tid & 63) == 0) red[tid >> 6] = lsum;
    __syncthreads();
    lsum = red[0] + red[1] + red[2] + red[3];
    const float inv = 1.0f / lsum;
    #pragma unroll
    for (int i = 0; i < 8; ++i)
        if (i < nc) row[tid + i * 256] = f2bf(vals[i] * inv);
}

extern "C" void kernel_launch(void* const* d_in, const int* in_sizes, int n_in,
                              void* d_out, int out_size, void* d_ws, size_t ws_size,
                              hipStream_t stream)
{
    const float* hidden = (const float*)d_in[0];
    const float* w_qkv  = (const float*)d_in[1];
    const float* w_out  = (const float*)d_in[2];
    const int*   pos    = (const int*)d_in[3];
    float* out = (float*)d_out;

    const int Bn = 2, S = 2048, E = 4096, H = 16;
    const int N3 = 3 * E;  // 12288
    const int Z = Bn * H;  // 32 flattened (batch, head)
    const size_t per_z = (size_t)S * S * 2;  // 8 MiB

    dim3 blk(256);
    dim3 blk2(512);

    // ---------------- Tier A: batch-fused (needs >= 328 MiB) ----------------
    const size_t fixedA =
        (size_t)N3 * E * 2 +        // wqkvT 96M
        (size_t)E * E * 2 +         // woutT 32M
        (size_t)Bn * S * E * 2 +    // hb 32M
        (size_t)Bn * S * N3 * 2 +   // qkvb 96M
        (size_t)Z * 256 * S * 2 +   // vT 32M
        (size_t)Bn * S * E * 2;     // attnb 32M

    if (ws_size >= fixedA + per_z) {
        u16* wqkvT = (u16*)d_ws;
        u16* woutT = wqkvT + (size_t)N3 * E;
        u16* hb    = woutT + (size_t)E * E;
        u16* qkvb  = hb + (size_t)Bn * S * E;
        u16* vT    = qkvb + (size_t)Bn * S * N3;
        u16* attnb = vT + (size_t)Z * 256 * S;
        u16* sc    = attnb + (size_t)Bn * S * E;

        int zc = (int)((ws_size - fixedA) / per_z);
        if (zc > Z) zc = Z;
        while (Z % zc) --zc;   // zc in {32,16,8,4,2,1}

        // one-time conversions/transposes
        cvt_kernel<<<dim3(2048), blk, 0, stream>>>(hidden, hb, (long)Bn * S * E / 8);
        transpose_kernel<float><<<dim3(N3 / 64, E / 64, 1), blk, 0, stream>>>(
            w_qkv, N3, 0, 0L, wqkvT, E, 0L);
        transpose_kernel<float><<<dim3(E / 64, E / 64, 1), blk, 0, stream>>>(
            w_out, E, 0, 0L, woutT, E, 0L);

        // 1. QKV projection, both batches: 768 blocks = 3 full rounds
        gemm256<u16><<<dim3(N3 / 256, S / 256, Bn), blk2, 0, stream>>>(
            hb, (long)S * E, 0, E,
            wqkvT, 0L, 0, E,
            qkvb, (long)S * N3, 0, N3, E, 0, 0);

        // 2. rotary (+ q *= 1/16), both batches
        rotary_kernel<<<dim3(Bn * S), blk, 0, stream>>>(qkvb, pos);

        // 3. V^T per (batch, head): [2048,256] -> [256,2048]
        transpose_kernel<u16><<<dim3(256 / 64, S / 64, Z), blk, 0, stream>>>(
            qkvb, N3, 1, (long)S * N3, vT, S, (long)256 * S);

        // 4. attention, z-chunked over flattened (batch, head)
        for (int z0 = 0; z0 < Z; z0 += zc) {
            gemm256<u16><<<dim3(S / 256, S / 256, zc), blk2, 0, stream>>>(
                qkvb, (long)S * N3, 1, N3,
                qkvb + 2048, (long)S * N3, 1, N3,
                sc, (long)S * S, 0, S,
                256, 1, z0);
            softmax_kernel<<<dim3(S, zc), blk, 0, stream>>>(sc);
            gemm256<u16><<<dim3(1, S / 256, zc), blk2, 0, stream>>>(
                sc, (long)S * S, 0, S,
                vT, (long)256 * S, 3, S,
                attnb, (long)S * E, 4, E,
                S, 2, z0);
        }

        // 5. output projection, both batches: 256 blocks = 1 full round
        gemm256<float><<<dim3(E / 256, S / 256, Bn), blk2, 0, stream>>>(
            attnb, (long)S * E, 0, E,
            woutT, 0L, 0, E,
            out, (long)S * E, 0, E, E, 0, 0);
        return;
    }

    // ---------------- Tier B: per-batch fast path (needs >= 248 MiB) ----------------
    const size_t fixedB =
        (size_t)N3 * E * 2 +        // wqkvT
        (size_t)E * E * 2 +         // woutT
        (size_t)Bn * S * E * 2 +    // hb
        (size_t)S * N3 * 2 +        // qkvb (one batch)
        (size_t)H * 256 * S * 2 +   // vT (one batch)
        (size_t)S * E * 2;          // attnb (one batch)

    if (ws_size >= fixedB + per_z) {
        u16* wqkvT = (u16*)d_ws;
        u16* woutT = wqkvT + (size_t)N3 * E;
        u16* hb    = woutT + (size_t)E * E;
        u16* qkvb  = hb + (size_t)Bn * S * E;
        u16* vT    = qkvb + (size_t)S * N3;
        u16* attnb = vT + (size_t)H * 256 * S;
        u16* sc    = attnb + (size_t)S * E;

        int hc = (int)((ws_size - fixedB) / per_z);
        if (hc > H) hc = H;
        while (H % hc) --hc;

        cvt_kernel<<<dim3(2048), blk, 0, stream>>>(hidden, hb, (long)Bn * S * E / 8);
        transpose_kernel<float><<<dim3(N3 / 64, E / 64, 1), blk, 0, stream>>>(
            w_qkv, N3, 0, 0L, wqkvT, E, 0L);
        transpose_kernel<float><<<dim3(E / 64, E / 64, 1), blk, 0, stream>>>(
            w_out, E, 0, 0L, woutT, E, 0L);

        for (int b = 0; b < Bn; ++b) {
            gemm256<u16><<<dim3(N3 / 256, S / 256, 1), blk2, 0, stream>>>(
                hb + (size_t)b * S * E, 0L, 0, E,
                wqkvT, 0L, 0, E,
                qkvb, 0L, 0, N3, E, 0, 0);

            rotary_kernel<<<dim3(S), blk, 0, stream>>>(qkvb, pos + (size_t)b * S);

            transpose_kernel<u16><<<dim3(256 / 64, S / 64, H), blk, 0, stream>>>(
                qkvb, N3, 1, 0L, vT, S, (long)256 * S);

            for (int h0 = 0; h0 < H; h0 += hc) {
                gemm256<u16><<<dim3(S / 256, S / 256, hc), blk2, 0, stream>>>(
                    qkvb, 0L, 1, N3,
                    qkvb + 2048, 0L, 1, N3,
                    sc, (long)S * S, 0, S,
                    256, 1, h0);
                softmax_kernel<<<dim3(S, hc), blk, 0, stream>>>(sc);
                gemm256<u16><<<dim3(1, S / 256, hc), blk2, 0, stream>>>(
                    sc, (long)S * S, 0, S,
                    vT, (long)256 * S, 3, S,
                    attnb, 0L, 4, E,
                    S, 2, h0);
            }

            gemm256<float><<<dim3(E / 256, S / 256, 1), blk2, 0, stream>>>(
                attnb, 0L, 0, E,
                woutT, 0L, 0, E,
                out + (size_t)b * S * E, 0L, 0, E, E, 0, 0);
        }
        return;
    }

    // ---------------- Tier C: fallback ----------------
    u16* qkvb  = (u16*)d_ws;
    u16* attnb = qkvb + (size_t)S * N3;
    u16* sc    = attnb + (size_t)S * E;

    const size_t need_base = ((size_t)S * N3 + (size_t)S * E) * 2;
    int hc = 1;
    if (ws_size > need_base) {
        size_t avail = ws_size - need_base;
        hc = (int)(avail / per_z);
        if (hc < 1) hc = 1;
        if (hc > H) hc = H;
        while (H % hc) --hc;
    }

    for (int b = 0; b < Bn; ++b) {
        gemm_bf16<false><<<dim3(N3 / BN, S / BM, 1), blk, 0, stream>>>(
            hidden + (size_t)b * S * E, 0L, 0, E,
            w_qkv, 0L, 0, N3,
            qkvb, 0L, N3, E, 0, 0);

        rotary_kernel<<<dim3(S), blk, 0, stream>>>(qkvb, pos + (size_t)b * S);

        for (int h0 = 0; h0 < H; h0 += hc) {
            gemm_bf16<true><<<dim3(S / BN, S / BM, hc), blk, 0, stream>>>(
                qkvb, 0L, 1, N3,
                qkvb, 0L, 3, N3,
                sc, (long)S * S, S,
                256, 1, h0);
            softmax_kernel<<<dim3(S, hc), blk, 0, stream>>>(sc);
            gemm_bf16<false><<<dim3(2, S / BM, hc), blk, 0, stream>>>(
                sc, (long)S * S, 0, S,
                qkvb, 0L, 2, N3,
                attnb + (size_t)h0 * 256, 256L, E,
                S, 2, h0);
        }

        gemm_bf16<false><<<dim3(E / BN, S / BM, 1), blk, 0, stream>>>(
            attnb, 0L, 0, E,
            w_out, 0L, 0, E,
            out + (size_t)b * S * E, 0L, E, E, 0, 0);
    }
}